// Round 1
// baseline (477.506 us; speedup 1.0000x reference)
//
#include <hip/hip_runtime.h>

typedef unsigned int uint;
typedef unsigned short ushort;
typedef __attribute__((ext_vector_type(8))) short b16x8;
typedef __attribute__((ext_vector_type(4))) float f32x4;

// ws byte offsets
#define PHIUT_OFF 0u
#define SQLP_OFF  524288u
#define SMU_OFF   (524288u + 65536u)
#define WBUF_OFF  (524288u + 131072u)
#define KLSO_OFF  (524288u + 131072u + 1048576u)

__device__ __forceinline__ ushort f2bf(float x){
  union { float f; uint u; } v; v.f = x;
  uint r = v.u + 0x7fffu + ((v.u >> 16) & 1u);
  return (ushort)(r >> 16);
}
__device__ __forceinline__ float bflo(uint u){ union { uint uu; float f; } v; v.uu = u << 16; return v.f; }
__device__ __forceinline__ float bfhi(uint u){ union { uint uu; float f; } v; v.uu = u & 0xffff0000u; return v.f; }

// C = A_rows · B_rows^T (NT), 128x128x128, bf16 MFMA 16x16x32.
// wave wv owns tile-rows {2wv, 2wv+1} x all 8 tile-cols.
__device__ __forceinline__ void mfma128(const ushort (*A)[136], const ushort (*B)[136],
                                        f32x4 acc[2][8], int wv, int lane){
  const int lr = lane & 15, lk = lane >> 4;
  #pragma unroll
  for (int ti = 0; ti < 2; ++ti)
    #pragma unroll
    for (int tj = 0; tj < 8; ++tj)
      acc[ti][tj] = (f32x4){0.f, 0.f, 0.f, 0.f};
  #pragma unroll
  for (int kk = 0; kk < 4; ++kk){
    const int kof = kk * 32 + lk * 8;
    b16x8 a0 = *(const b16x8*)&A[(wv * 2 + 0) * 16 + lr][kof];
    b16x8 a1 = *(const b16x8*)&A[(wv * 2 + 1) * 16 + lr][kof];
    #pragma unroll
    for (int tj = 0; tj < 8; ++tj){
      b16x8 bf = *(const b16x8*)&B[tj * 16 + lr][kof];
      acc[0][tj] = __builtin_amdgcn_mfma_f32_16x16x32_bf16(a0, bf, acc[0][tj], 0, 0, 0);
      acc[1][tj] = __builtin_amdgcn_mfma_f32_16x16x32_bf16(a1, bf, acc[1][tj], 0, 0, 0);
    }
  }
}

// ---------------- K0: prep (phiU^T bf16, exp(lp/2), exp(lp/2)*mu) ----------------
__global__ void k0_prep(const float* __restrict__ U, const float* __restrict__ mu,
                        const float* __restrict__ lp, ushort* __restrict__ phiUT,
                        float* __restrict__ sqlp, float* __restrict__ smu)
{
  __shared__ __align__(16) ushort T0[128][132];
  const int tid = threadIdx.x;
  const int bid = blockIdx.x;
  if (bid < 16){
    const float* Us = U + ((size_t)bid << 14);
    for (int e = tid * 4; e < 16384; e += 1024){
      f32x4 v = *(const f32x4*)&Us[e];
      int m = e >> 7, d = e & 127;
      uint p0 = (uint)f2bf(fmaxf(v[0], 0.f)) | ((uint)f2bf(fmaxf(v[1], 0.f)) << 16);
      uint p1 = (uint)f2bf(fmaxf(v[2], 0.f)) | ((uint)f2bf(fmaxf(v[3], 0.f)) << 16);
      uint2 pv; pv.x = p0; pv.y = p1;
      *(uint2*)&T0[m][d] = pv;
    }
    __syncthreads();
    ushort* op = phiUT + ((size_t)bid << 14);
    for (int e = tid; e < 16384; e += 256){
      int d = e >> 7, m2 = e & 127;
      op[e] = T0[m2][d];
    }
  } else {
    int idx = ((bid - 16) << 8) + tid;
    float l = lp[idx], m = mu[idx];
    float ex = expf(0.5f * l);
    sqlp[idx] = ex;
    smu[idx]  = ex * m;
  }
}

// ---------------- K2: per-(s,o) factorization ----------------
// Reversed space: B = J A J = Wt·Wt^T + I with Wt[d'] = sqrtLp ⊙ phiUT[127-d'].
// LDL: B = L~ D L~^T ; S = L~^{-1} (in place). Then:
//   logdet_prec = Σ log d_k ; tr(q_cov) = Σ_i ||S row i||²/d_i
//   p = S v~ ; qmu~ = S^T (p/d) ; w~ = qmu~ + S^T (eps~/√d) ; w[d] = w~[127-d]
__global__ __launch_bounds__(256, 2) void k2_factor(
    const ushort* __restrict__ phiUT, const float* __restrict__ sqlp,
    const float* __restrict__ smu, const float* __restrict__ eps,
    float* __restrict__ wout, float* __restrict__ klso)
{
  __shared__ __align__(16) float Bm[128][132];
  __shared__ __align__(16) float Tscr[4][2][16][16];
  __shared__ __align__(16) float svec[128];
  __shared__ __align__(16) float smuv[128];
  __shared__ __align__(16) float epsv[128];
  __shared__ __align__(16) float utlv[128];
  __shared__ __align__(16) float dvec[128];
  __shared__ __align__(16) float pvec[128];
  __shared__ __align__(16) float qmuv[128];
  __shared__ __align__(16) float wtv[128];
  float* trv = smuv;  // smuv dead after phase 3
  float* red = svec;  // svec dead after phase 2
  ushort (*Wt)[136] = (ushort (*)[136])&Bm[0][0];

  const int tid  = threadIdx.x;
  const int lane = tid & 63;
  const int wv   = tid >> 6;
  const int s    = blockIdx.x >> 7;
  const int o    = blockIdx.x & 127;

  // 4x4-tile triangle table for trailing updates (2 entries/thread)
  int tta[2], ttb[2];
  #pragma unroll
  for (int it = 0; it < 2; ++it){
    int f = tid + (it << 8);
    int a = (int)((sqrtf((float)(8 * f + 1)) - 1.0f) * 0.5f);
    while ((a + 1) * (a + 2) / 2 <= f) ++a;
    while (a * (a + 1) / 2 > f) --a;
    tta[it] = a;
    ttb[it] = f - a * (a + 1) / 2;
  }

  // phase 1: vectors
  if (tid < 128){
    svec[tid] = sqlp[(o << 7) + tid];
    epsv[tid] = eps[(((size_t)s * 128 + o) << 7) + 127 - tid];
  } else {
    int t2 = tid - 128;
    smuv[t2] = smu[(o << 7) + t2];
  }
  __syncthreads();

  // phase 2: Wt fill (reversed rows, scaled, bf16)
  for (int e = tid * 8; e < 16384; e += 2048){
    int dp = e >> 7, m = e & 127;
    const ushort* srcp = phiUT + (((size_t)s) << 14) + ((size_t)(127 - dp) << 7) + m;
    uint4 raw = *(const uint4*)srcp;
    f32x4 c0 = *(f32x4*)&svec[m];
    f32x4 c1 = *(f32x4*)&svec[m + 4];
    uint o0 = (uint)f2bf(bflo(raw.x) * c0[0]) | ((uint)f2bf(bfhi(raw.x) * c0[1]) << 16);
    uint o1 = (uint)f2bf(bflo(raw.y) * c0[2]) | ((uint)f2bf(bfhi(raw.y) * c0[3]) << 16);
    uint o2 = (uint)f2bf(bflo(raw.z) * c1[0]) | ((uint)f2bf(bfhi(raw.z) * c1[1]) << 16);
    uint o3 = (uint)f2bf(bflo(raw.w) * c1[2]) | ((uint)f2bf(bfhi(raw.w) * c1[3]) << 16);
    uint4 ov; ov.x = o0; ov.y = o1; ov.z = o2; ov.w = o3;
    *(uint4*)&Wt[dp][m] = ov;
  }
  __syncthreads();

  // phase 3: v~ = Wt · (sqrtLp ⊙ mu)
  if (tid < 128){
    float acc3 = 0.f;
    for (int m = 0; m < 128; m += 8){
      uint4 raw = *(uint4*)&Wt[tid][m];
      f32x4 u0 = *(f32x4*)&smuv[m];
      f32x4 u1 = *(f32x4*)&smuv[m + 4];
      acc3 += bflo(raw.x) * u0[0] + bfhi(raw.x) * u0[1]
            + bflo(raw.y) * u0[2] + bfhi(raw.y) * u0[3]
            + bflo(raw.z) * u1[0] + bfhi(raw.z) * u1[1]
            + bflo(raw.w) * u1[2] + bfhi(raw.w) * u1[3];
    }
    utlv[tid] = acc3;
  }
  __syncthreads();

  // phase 4: MFMA Gram
  f32x4 acc[2][8];
  mfma128(Wt, Wt, acc, wv, lane);
  __syncthreads();  // Wt reads complete before overwrite

  // phase 5: Bm = Gram + I (full matrix)
  {
    const int lr = lane & 15, lk = lane >> 4;
    #pragma unroll
    for (int ti = 0; ti < 2; ++ti){
      #pragma unroll
      for (int tj = 0; tj < 8; ++tj){
        int c = tj * 16 + lr;
        #pragma unroll
        for (int q = 0; q < 4; ++q){
          int r = (wv * 2 + ti) * 16 + lk * 4 + q;
          float v = acc[ti][tj][q];
          if (r == c) v += 1.0f;
          Bm[r][c] = v;
        }
      }
    }
  }

  // phase 6: blocked LDL (NB=8, 16 panels)
  const int pcc = tid & 7, prr = tid >> 3;
  for (int p = 0; p < 16; ++p){
    const int k0 = p << 3;
    for (int t = 0; t < 8; ++t){
      const int k = k0 + t;
      __syncthreads();
      float dk = Bm[k][k];
      if (tid == 0) dvec[k] = dk;
      if (t < 7){
        float rk = 1.0f / dk;
        int j = k + 1 + pcc;
        if (j < k0 + 8){
          float mval = Bm[j][k] * rk;
          for (int i = j + prr; i < 128; i += 32)
            Bm[i][j] -= Bm[i][k] * mval;
        }
      }
    }
    __syncthreads();
    {
      int k = k0 + pcc;
      float rk = 1.0f / dvec[k];
      for (int i = k + 1 + prr; i < 128; i += 32) Bm[i][k] *= rk;
      if (tid < 8) Bm[k0 + tid][k0 + tid] = 1.0f;
    }
    __syncthreads();
    const int base = k0 + 8;
    const int n = 128 - base;
    if (n > 0){
      const int ntile = n >> 2;
      const int tiles = (ntile * (ntile + 1)) >> 1;
      f32x4 dv0 = *(f32x4*)&dvec[k0];
      f32x4 dv1 = *(f32x4*)&dvec[k0 + 4];
      #pragma unroll
      for (int it = 0; it < 2; ++it){
        int f = tid + (it << 8);
        if (f < tiles){
          int i0 = base + (tta[it] << 2), j0 = base + (ttb[it] << 2);
          f32x4 wi[4][2], aj[4][2];
          #pragma unroll
          for (int r = 0; r < 4; ++r){
            wi[r][0] = *(f32x4*)&Bm[i0 + r][k0] * dv0;
            wi[r][1] = *(f32x4*)&Bm[i0 + r][k0 + 4] * dv1;
            aj[r][0] = *(f32x4*)&Bm[j0 + r][k0];
            aj[r][1] = *(f32x4*)&Bm[j0 + r][k0 + 4];
          }
          #pragma unroll
          for (int r = 0; r < 4; ++r){
            f32x4 cur = *(f32x4*)&Bm[i0 + r][j0];
            #pragma unroll
            for (int q = 0; q < 4; ++q){
              f32x4 prod = wi[r][0] * aj[q][0] + wi[r][1] * aj[q][1];
              cur[q] -= prod[0] + prod[1] + prod[2] + prod[3];
            }
            *(f32x4*)&Bm[i0 + r][j0] = cur;
          }
        }
      }
    }
  }
  __syncthreads();

  // zero strict-upper of diag 16x16 blocks (8b reads full rows of them)
  for (int e = tid; e < 2048; e += 256){
    int b = e >> 8, r = (e >> 4) & 15, c = e & 15;
    if (c > r) Bm[(b << 4) + r][(b << 4) + c] = 0.0f;
  }

  // phase 8a: invert 16x16 unit-lower diag blocks in place
  for (int st = 1; st < 16; ++st){
    __syncthreads();
    float val = 0.f; int wi8 = -1, wj8 = 0;
    if (tid < 128){
      int b = tid >> 4, c = tid & 15;
      if (c < st){
        int ib = b << 4;
        int i = ib + st, j = ib + c;
        float a2 = Bm[i][j];
        for (int k = c + 1; k < st; ++k) a2 += Bm[i][ib + k] * Bm[ib + k][j];
        val = -a2; wi8 = i; wj8 = j;
      }
    }
    __syncthreads();
    if (wi8 >= 0) Bm[wi8][wj8] = val;
  }

  // phase 8b: off-diagonal blocks of S = L~^{-1}, in place
  {
    const int xr = lane >> 2;
    const int xc = (lane & 3) << 2;
    for (int I = 1; I < 8; ++I){
      __syncthreads();
      for (int J = wv; J < I; J += 4){
        int slot = J >> 2;
        f32x4 tv = (f32x4){0.f, 0.f, 0.f, 0.f};
        for (int K = J; K < I; ++K){
          #pragma unroll
          for (int kk = 0; kk < 16; ++kk){
            float l = Bm[(I << 4) + xr][(K << 4) + kk];
            f32x4 srow = *(f32x4*)&Bm[(K << 4) + kk][(J << 4) + xc];
            tv += l * srow;
          }
        }
        *(f32x4*)&Tscr[wv][slot][xr][xc] = tv;
      }
      __syncthreads();
      for (int J = wv; J < I; J += 4){
        int slot = J >> 2;
        f32x4 x = *(f32x4*)&Tscr[wv][slot][xr][xc];
        for (int k = 0; k < xr; ++k){
          float sik = Bm[(I << 4) + xr][(I << 4) + k];
          x += sik * (*(f32x4*)&Tscr[wv][slot][k][xc]);
        }
        *(f32x4*)&Bm[(I << 4) + xr][(J << 4) + xc] = -x;
      }
    }
  }
  __syncthreads();

  // phase 9a/9b: row sweeps: trace partials, p = S v~
  if (tid < 128){
    int i = tid;
    float asq = 0.f, ap = 0.f;
    for (int j4 = 0; j4 <= (i >> 2); ++j4){
      f32x4 v = *(f32x4*)&Bm[i][j4 << 2];
      f32x4 uv = *(f32x4*)&utlv[j4 << 2];
      #pragma unroll
      for (int q = 0; q < 4; ++q){
        int j = (j4 << 2) + q;
        bool ok = (j <= i);
        float sv = ok ? v[q] : 0.f;
        asq += sv * sv;
        ap  += sv * (ok ? uv[q] : 0.f);
      }
    }
    pvec[i] = ap;
    trv[i] = asq / dvec[i];
  }
  __syncthreads();
  if (tid < 128){
    utlv[tid] = pvec[tid] / dvec[tid];          // g = p / d
    epsv[tid] = epsv[tid] * rsqrtf(dvec[tid]);  // h = eps~ / sqrt(d)
  }
  __syncthreads();
  // phase 9c/9d: column sweeps: qmu~ = S^T g ; w~ = qmu~ + S^T h
  if (tid < 128){
    int j = tid;
    float aq = 0.f, aw = 0.f;
    for (int i = j; i < 128; ++i){
      float sij = Bm[i][j];
      aq += sij * utlv[i];
      aw += sij * epsv[i];
    }
    qmuv[j] = aq;
    wtv[j] = aq + aw;
  }
  __syncthreads();
  // phase 9e: reductions + kl; 9f: write w
  float ra = 0.f, rb = 0.f, rc = 0.f;
  if (tid < 128){
    ra = trv[tid];
    float q = qmuv[tid];
    rb = q * q;
    rc = logf(dvec[tid]);
  }
  #pragma unroll
  for (int off = 32; off > 0; off >>= 1){
    ra += __shfl_xor(ra, off);
    rb += __shfl_xor(rb, off);
    rc += __shfl_xor(rc, off);
  }
  if (lane == 0){
    red[wv * 4 + 0] = ra; red[wv * 4 + 1] = rb; red[wv * 4 + 2] = rc;
  }
  __syncthreads();
  if (tid == 0){
    float tr = red[0] + red[4] + red[8]  + red[12];
    float q2 = red[1] + red[5] + red[9]  + red[13];
    float ld = red[2] + red[6] + red[10] + red[14];
    klso[(s << 7) + o] = 0.5f * (tr + q2 - 128.0f + ld);
  }
  if (tid < 128)
    wout[(((size_t)(s << 7) + o) << 7) + tid] = wtv[127 - tid];
}

// ---------------- K3: F_out / U_out GEMMs ----------------
__global__ __launch_bounds__(256, 2) void k3_outs(
    const float* __restrict__ F, const float* __restrict__ U,
    const float* __restrict__ wbuf, float* __restrict__ out)
{
  __shared__ __align__(16) ushort Ab[128][136];
  __shared__ __align__(16) ushort Wb[128][136];
  const int tid = threadIdx.x;
  const int lane = tid & 63, wv = tid >> 6;
  const int bid = blockIdx.x;
  const float* src;
  float* dst;
  int s;
  if (bid < 512){
    s = bid >> 5;
    int t = bid & 31;
    size_t off = (((size_t)s * 4096) + (size_t)t * 128) * 128;
    src = F + off;
    dst = out + off;
  } else {
    s = bid - 512;
    src = U + ((size_t)s << 14);
    dst = out + (size_t)8388608 + ((size_t)s << 14);
  }
  for (int e = tid * 4; e < 16384; e += 1024){
    f32x4 v = *(const f32x4*)&src[e];
    uint p0 = (uint)f2bf(fmaxf(v[0], 0.f)) | ((uint)f2bf(fmaxf(v[1], 0.f)) << 16);
    uint p1 = (uint)f2bf(fmaxf(v[2], 0.f)) | ((uint)f2bf(fmaxf(v[3], 0.f)) << 16);
    uint2 pv; pv.x = p0; pv.y = p1;
    *(uint2*)&Ab[e >> 7][e & 127] = pv;
  }
  const float* wsrc = wbuf + ((size_t)s << 14);
  for (int e = tid * 4; e < 16384; e += 1024){
    f32x4 v = *(const f32x4*)&wsrc[e];
    uint p0 = (uint)f2bf(v[0]) | ((uint)f2bf(v[1]) << 16);
    uint p1 = (uint)f2bf(v[2]) | ((uint)f2bf(v[3]) << 16);
    uint2 pv; pv.x = p0; pv.y = p1;
    *(uint2*)&Wb[e >> 7][e & 127] = pv;
  }
  __syncthreads();
  f32x4 acc[2][8];
  mfma128(Ab, Wb, acc, wv, lane);
  const int lr = lane & 15, lk = lane >> 4;
  #pragma unroll
  for (int ti = 0; ti < 2; ++ti){
    #pragma unroll
    for (int tj = 0; tj < 8; ++tj){
      int c = tj * 16 + lr;
      #pragma unroll
      for (int q = 0; q < 4; ++q){
        int r = (wv * 2 + ti) * 16 + lk * 4 + q;
        dst[(size_t)r * 128 + c] = acc[ti][tj][q];
      }
    }
  }
}

// ---------------- K4: kl reduction ----------------
__global__ void k4_klred(const float* __restrict__ klso, float* __restrict__ klout){
  __shared__ float sums[16][17];
  const int t = threadIdx.x;
  int s = t >> 4, ch = t & 15;
  float a = 0.f;
  for (int q = 0; q < 8; ++q) a += klso[(s << 7) + ch * 8 + q];
  sums[s][ch] = a;
  __syncthreads();
  if (t < 16){
    float r = 0.f;
    for (int c = 0; c < 16; ++c) r += sums[t][c];
    klout[t] = r;
  }
}

extern "C" void kernel_launch(void* const* d_in, const int* in_sizes, int n_in,
                              void* d_out, int out_size, void* d_ws, size_t ws_size,
                              hipStream_t stream) {
  const float* F   = (const float*)d_in[0];
  const float* U   = (const float*)d_in[1];
  const float* mu  = (const float*)d_in[2];
  const float* lp  = (const float*)d_in[3];
  const float* eps = (const float*)d_in[4];
  float* out = (float*)d_out;
  char* ws = (char*)d_ws;
  ushort* phiUT = (ushort*)(ws + PHIUT_OFF);
  float* sqlp = (float*)(ws + SQLP_OFF);
  float* smu  = (float*)(ws + SMU_OFF);
  float* wbuf = (float*)(ws + WBUF_OFF);
  float* klso = (float*)(ws + KLSO_OFF);

  k0_prep<<<dim3(80), dim3(256), 0, stream>>>(U, mu, lp, phiUT, sqlp, smu);
  k2_factor<<<dim3(2048), dim3(256), 0, stream>>>(phiUT, sqlp, smu, eps, wbuf, klso);
  k3_outs<<<dim3(528), dim3(256), 0, stream>>>(F, U, wbuf, out);
  k4_klred<<<dim3(1), dim3(256), 0, stream>>>(klso, out + 8650752);
}